// Round 6
// baseline (11829.597 us; speedup 1.0000x reference)
//
#include <hip/hip_runtime.h>
#include <cmath>

#define SS 512
#define BB 32
#define EE 128
#define HH 256
#define VV 10000
#define NROWS (SS*BB)   // 16384
#define VPAD 10048

typedef unsigned short ushort_t;
typedef __attribute__((ext_vector_type(8))) short bf16x8;
typedef __attribute__((ext_vector_type(4))) float f32x4;

#define MFMA(a,b,c) __builtin_amdgcn_mfma_f32_16x16x32_bf16((a),(b),(c),0,0,0)

__device__ __forceinline__ ushort_t f2bf(float x) {
    unsigned u = __float_as_uint(x);
    u = (u + 0x7FFFu + ((u >> 16) & 1u)) >> 16;   // RNE
    return (ushort_t)u;
}
__device__ __forceinline__ float bf2f(ushort_t h) {
    return __uint_as_float(((unsigned)h) << 16);
}
__device__ __forceinline__ float sigf(float x) { return 1.0f / (1.0f + __expf(-x)); }
__device__ __forceinline__ float tanhf_(float x) { return 1.0f - 2.0f / (__expf(2.0f * x) + 1.0f); }

// ---------------- zgemm: layer-1 x-part, output bf16 PRE-SWIZZLED ----------------
// Zsw[t][slot512][cellg64]: slot = w*64+q*16+n16 (w=u>>5,n16=u&15,q=(b>>2)&3),
// cellg = ((ug2*2+m)*4+r)*4+g with ug2=(u>>4)&1, m=b>>4, r=b&3, col=g*256+u.
__global__ __launch_bounds__(256)
void zgemm_sw(const float* __restrict__ Wk, const float* __restrict__ bias,
              const float* __restrict__ xin, const int* __restrict__ idx,
              ushort_t* __restrict__ Zsw)
{
    __shared__ float A[16][256];
    const int tid = threadIdx.x;
    const int m0 = blockIdx.x * 16;
    for (int i = tid; i < 16 * EE; i += 256) {
        const int r = i >> 7, cc = i & (EE - 1);
        const int m = m0 + r;
        const int t = m >> 5, b = m & (BB - 1);
        const int id = idx[b * SS + t];
        A[r][cc] = xin[(size_t)id * EE + cc];
    }
    __syncthreads();
    const float4 b4 = ((const float4*)bias)[tid];
    float4 acc[16];
#pragma unroll
    for (int i = 0; i < 16; i++) acc[i] = b4;
    for (int r = 0; r < EE; r++) {
        const float4 w = ((const float4*)(Wk + (size_t)r * 1024))[tid];
#pragma unroll
        for (int i = 0; i < 16; i++) {
            const float a = A[i][r];
            acc[i].x += a * w.x; acc[i].y += a * w.y;
            acc[i].z += a * w.z; acc[i].w += a * w.w;
        }
    }
    const int t = m0 >> 5, b0 = m0 & 31;
#pragma unroll
    for (int i = 0; i < 16; i++) {
        const int b = b0 + i;
        const float v4[4] = {acc[i].x, acc[i].y, acc[i].z, acc[i].w};
#pragma unroll
        for (int jj = 0; jj < 4; jj++) {
            const int col = 4 * tid + jj;
            const int g = col >> 8, u = col & 255;
            const int w = u >> 5, ug2 = (u >> 4) & 1, n16 = u & 15;
            const int slot = w * 64 + ((b >> 2) & 3) * 16 + n16;
            const int cell = ((ug2 * 2 + (b >> 4)) * 4) + (b & 3);
            Zsw[((size_t)t * 512 + slot) * 64 + cell * 4 + g] = f2bf(v4[jj]);
        }
    }
}

// ---------------- generic fp32[256 x 1024] -> bf16 [1024][256] transpose --------
__global__ __launch_bounds__(256)
void wtgen(const float* __restrict__ src, ushort_t* __restrict__ dst)
{
    __shared__ float tile[64][65];
    const int tid = threadIdx.x;
    const int n0 = blockIdx.x * 64, k0 = blockIdx.y * 64;
    for (int i = tid; i < 4096; i += 256) {
        const int kk = i >> 6, nn = i & 63;
        tile[kk][nn] = src[(size_t)(k0 + kk) * 1024 + n0 + nn];
    }
    __syncthreads();
    for (int i = tid; i < 4096; i += 256) {
        const int nn = i >> 6, kk = i & 63;
        dst[(size_t)(n0 + nn) * 256 + k0 + kk] = f2bf(tile[kk][nn]);
    }
}

// ---------------- out_W -> bf16 transpose + padded bias (validated R3-R5) -------
__global__ __launch_bounds__(256)
void wtrans_kernel(const float* __restrict__ W, ushort_t* __restrict__ Wt)
{
    __shared__ float tile[64][65];
    const int tid = threadIdx.x;
    const int n0 = blockIdx.x * 64, k0 = blockIdx.y * 64;
    for (int i = tid; i < 4096; i += 256) {
        const int kk = i >> 6, nn = i & 63;
        const int n = n0 + nn;
        tile[kk][nn] = (n < VV) ? W[(size_t)(k0 + kk) * VV + n] : 0.f;
    }
    __syncthreads();
    for (int i = tid; i < 4096; i += 256) {
        const int nn = i >> 6, kk = i & 63;
        Wt[(size_t)(n0 + nn) * 256 + k0 + kk] = f2bf(tile[kk][nn]);
    }
}

__global__ __launch_bounds__(256)
void obset_kernel(const float* __restrict__ ob, float* __restrict__ obp)
{
    const int v = blockIdx.x * 256 + threadIdx.x;
    if (v < VPAD) obp[v] = (v < VV) ? ob[v] : -INFINITY;
}

// ---------------- pipelined LSTM: 2 recurrence blocks + 128 xgemm blocks --------
// Block 0: layer-1 recurrence (h in LDS, no cross-block dep). Publishes c1 every
// 8 steps. Block 1: layer-2 recurrence, consumes pre-swizzled xz chunks (poll
// once per 4 steps, one-directional). Blocks 2..129: layer-2 x-part GEMM chunks.
__global__ __launch_bounds__(512, 2)
void pipe_kernel(const ushort_t* __restrict__ W1h, const ushort_t* __restrict__ W2h,
                 const ushort_t* __restrict__ W2x, const float* __restrict__ b1v,
                 const int* __restrict__ lens, const ushort_t* __restrict__ Zsw,
                 ushort_t* __restrict__ out1, ushort_t* __restrict__ xzsw,
                 ushort_t* __restrict__ h2bf,
                 unsigned* __restrict__ c1, unsigned* __restrict__ xzf)
{
    __shared__ ushort_t hAs[2][32 * 264];
    const int tid = threadIdx.x;
    const int w = tid >> 6, lane = tid & 63;
    const int q = lane >> 4, n16 = lane & 15;
    const int blk = blockIdx.x;

    if (blk < 2) {
        // ================= recurrence (layer blk) =================
        const ushort_t* Wh = blk ? W2h : W1h;
        const ushort_t* zsrc = blk ? xzsw : Zsw;
        ushort_t* outp = blk ? h2bf : out1;
        for (int i = tid; i < 2 * 32 * 264; i += 512) ((ushort_t*)hAs)[i] = 0;
        const int colA = w * 32 + n16, colB = colA + 16;
        bf16x8 Bv[3][8];                                   // gates 0..2 of colA, VGPR-resident
#pragma unroll
        for (int g = 0; g < 3; g++)
#pragma unroll
            for (int kb = 0; kb < 8; kb++)
                Bv[g][kb] = *(const bf16x8*)&Wh[(size_t)(g * 256 + colA) * 256 + kb * 32 + q * 8];
        float bz[8];
#pragma unroll
        for (int ug2 = 0; ug2 < 2; ug2++)
#pragma unroll
            for (int g = 0; g < 4; g++)
                bz[ug2 * 4 + g] = blk ? b1v[g * 256 + (ug2 ? colB : colA)] : 0.f;
        int len2[2][4];
#pragma unroll
        for (int m = 0; m < 2; m++)
#pragma unroll
            for (int r = 0; r < 4; r++) len2[m][r] = lens[m * 16 + q * 4 + r];
        float cst[16];
#pragma unroll
        for (int i = 0; i < 16; i++) cst[i] = 0.f;
        __syncthreads();

        for (int t = 0; t < SS; t++) {
            if (blk == 1 && (t & 3) == 0 && tid == 0) {    // chunk flag (one-directional)
                int it = 0;
                while (__hip_atomic_load(&xzf[t >> 2], __ATOMIC_RELAXED,
                                         __HIP_MEMORY_SCOPE_AGENT) == 0u) {
                    __builtin_amdgcn_s_sleep(2);
                    if (++it > 4000000) break;
                }
            }
            __syncthreads();                               // hA slot handoff + flag visible
            if (blk == 1 && (t & 3) == 0)
                __builtin_amdgcn_fence(__ATOMIC_ACQUIRE, "agent");
            if (blk == 0 && (t & 7) == 0 && t > 0 && tid == 0)
                __hip_atomic_store(c1, (unsigned)t, __ATOMIC_RELEASE,
                                   __HIP_MEMORY_SCOPE_AGENT);
            const int rd = (t + 1) & 1, wr = t & 1;

            // z / xz: 128 B per lane, contiguous (pre-swizzled)
            const ushort_t* zp = zsrc + ((size_t)t * 512 + tid) * 64;
            bf16x8 z8[8];
#pragma unroll
            for (int i = 0; i < 8; i++) z8[i] = *(const bf16x8*)(zp + i * 8);

            f32x4 C[16];
#pragma unroll
            for (int i = 0; i < 16; i++) C[i] = (f32x4){0.f, 0.f, 0.f, 0.f};
#pragma unroll 4
            for (int kb = 0; kb < 8; kb++) {
                const bf16x8 A0 = *(const bf16x8*)&hAs[rd][n16 * 264 + kb * 32 + q * 8];
                const bf16x8 A1 = *(const bf16x8*)&hAs[rd][(16 + n16) * 264 + kb * 32 + q * 8];
                const bf16x8 B3 = *(const bf16x8*)&Wh[(size_t)(3 * 256 + colA) * 256 + kb * 32 + q * 8];
                bf16x8 Bb[4];
#pragma unroll
                for (int g = 0; g < 4; g++)
                    Bb[g] = *(const bf16x8*)&Wh[(size_t)(g * 256 + colB) * 256 + kb * 32 + q * 8];
#pragma unroll
                for (int g = 0; g < 3; g++) {
                    C[g * 2 + 0] = MFMA(A0, Bv[g][kb], C[g * 2 + 0]);
                    C[g * 2 + 1] = MFMA(A1, Bv[g][kb], C[g * 2 + 1]);
                }
                C[6] = MFMA(A0, B3, C[6]);
                C[7] = MFMA(A1, B3, C[7]);
#pragma unroll
                for (int g = 0; g < 4; g++) {
                    C[8 + g * 2 + 0] = MFMA(A0, Bb[g], C[8 + g * 2 + 0]);
                    C[8 + g * 2 + 1] = MFMA(A1, Bb[g], C[8 + g * 2 + 1]);
                }
            }
            // gate math: 16 cells/lane
#pragma unroll
            for (int ug2 = 0; ug2 < 2; ug2++)
#pragma unroll
            for (int m = 0; m < 2; m++)
#pragma unroll
            for (int r = 0; r < 4; r++) {
                const int cell = (ug2 * 2 + m) * 4 + r;
                const float zi = bf2f((ushort_t)z8[(cell * 4 + 0) >> 3][(cell * 4 + 0) & 7]) + C[ug2 * 8 + 0 * 2 + m][r] + bz[ug2 * 4 + 0];
                const float zg = bf2f((ushort_t)z8[(cell * 4 + 1) >> 3][(cell * 4 + 1) & 7]) + C[ug2 * 8 + 1 * 2 + m][r] + bz[ug2 * 4 + 1];
                const float zf = bf2f((ushort_t)z8[(cell * 4 + 2) >> 3][(cell * 4 + 2) & 7]) + C[ug2 * 8 + 2 * 2 + m][r] + bz[ug2 * 4 + 2];
                const float zo = bf2f((ushort_t)z8[(cell * 4 + 3) >> 3][(cell * 4 + 3) & 7]) + C[ug2 * 8 + 3 * 2 + m][r] + bz[ug2 * 4 + 3];
                const float cn = sigf(zf + 1.0f) * cst[cell] + sigf(zi) * tanhf_(zg);
                const float hn = sigf(zo) * tanhf_(cn);
                const bool act = (t < len2[m][r]);
                cst[cell] = act ? cn : cst[cell];
                const int col = w * 32 + ug2 * 16 + n16;
                const int b = m * 16 + q * 4 + r;
                const ushort_t hb = f2bf(hn);
                hAs[wr][b * 264 + col] = act ? hb : hAs[rd][b * 264 + col];
                outp[(size_t)t * 8192 + b * 256 + col] = act ? hb : (ushort_t)0;
            }
        }
        if (blk == 0) {
            __syncthreads();                               // drain all waves' out1 stores
            if (tid == 0)
                __hip_atomic_store(c1, (unsigned)SS, __ATOMIC_RELEASE,
                                   __HIP_MEMORY_SCOPE_AGENT);
        }
    } else {
        // ================= layer-2 x-part GEMM, chunk of 4 timesteps =================
        const int c = blk - 2;                             // 0..127
        if (tid == 0) {
            int it = 0;
            while (__hip_atomic_load(c1, __ATOMIC_RELAXED,
                                     __HIP_MEMORY_SCOPE_AGENT) < (unsigned)(4 * c + 4)) {
                __builtin_amdgcn_s_sleep(8);
                if (++it > 4000000) break;
            }
        }
        __syncthreads();
        __builtin_amdgcn_fence(__ATOMIC_ACQUIRE, "agent");
        const int m0 = c * 128;
#pragma unroll 1
        for (int i = 0; i < 8; i++) {                      // nt = w*8+i
            const int n = (w * 8 + i) * 16 + n16;
            bf16x8 Bfr[8];
#pragma unroll
            for (int kb = 0; kb < 8; kb++)
                Bfr[kb] = *(const bf16x8*)&W2x[(size_t)n * 256 + kb * 32 + q * 8];
            f32x4 Cc[8];
#pragma unroll
            for (int mt = 0; mt < 8; mt++) {
                Cc[mt] = (f32x4){0.f, 0.f, 0.f, 0.f};
                bf16x8 Af[8];
#pragma unroll
                for (int kb = 0; kb < 8; kb++)
                    Af[kb] = *(const bf16x8*)&out1[(size_t)(m0 + mt * 16 + n16) * 256 + kb * 32 + q * 8];
#pragma unroll
                for (int kb = 0; kb < 8; kb++)
                    Cc[mt] = MFMA(Af[kb], Bfr[kb], Cc[mt]);
            }
            const int g = n >> 8, u = n & 255;
            const int wT = u >> 5, ug2 = (u >> 4) & 1;
#pragma unroll
            for (int mt = 0; mt < 8; mt++)
#pragma unroll
                for (int r = 0; r < 4; r++) {
                    const int row = m0 + mt * 16 + q * 4 + r;
                    const int tt = row >> 5, b = row & 31;
                    const int slot = wT * 64 + ((b >> 2) & 3) * 16 + n16;
                    const int cell = ((ug2 * 2 + (b >> 4)) * 4) + (b & 3);
                    xzsw[((size_t)tt * 512 + slot) * 64 + cell * 4 + g] = f2bf(Cc[mt][r]);
                }
        }
        __syncthreads();                                   // drain stores
        if (tid == 0)
            __hip_atomic_store(&xzf[c], 1u, __ATOMIC_RELEASE, __HIP_MEMORY_SCOPE_AGENT);
    }
}

// ---------------- MFMA bf16 fused projection + CE (validated R3-R5) ----------------
__global__ __launch_bounds__(256, 1)
void ce_kernel(const ushort_t* __restrict__ h2bf, const ushort_t* __restrict__ Wt,
               const float* __restrict__ obp, const int* __restrict__ y,
               const int* __restrict__ lens, float* __restrict__ out)
{
    __shared__ ushort_t h2t[64 * 264];
    __shared__ float lsw[4][64];
    __shared__ float tgt64[64];
    const int tid = threadIdx.x;
    const int w = tid >> 6, lane = tid & 63;
    const int q = lane >> 4, n16 = lane & 15;
    const int m0 = blockIdx.x * 64;

    for (int i = tid; i < 64 * 32; i += 256) {
        const int r = i >> 5, s = i & 31;
        *(uint4*)&h2t[r * 264 + s * 8] = *(const uint4*)(h2bf + (size_t)(m0 + r) * 256 + s * 8);
    }
    if (tid < 64) tgt64[tid] = 0.f;
    __syncthreads();

    bf16x8 A[4][8];
#pragma unroll
    for (int mt = 0; mt < 4; mt++) {
        const int row = mt * 16 + n16;
#pragma unroll
        for (int kb = 0; kb < 8; kb++)
            A[mt][kb] = *(const bf16x8*)&h2t[row * 264 + kb * 32 + q * 8];
    }
    int yv[16];
#pragma unroll
    for (int mt = 0; mt < 4; mt++)
#pragma unroll
        for (int r = 0; r < 4; r++) {
            const int m = m0 + mt * 16 + q * 4 + r;
            yv[mt * 4 + r] = y[(m & 31) * SS + (m >> 5)];
        }
    float lsum[16];
#pragma unroll
    for (int i = 0; i < 16; i++) lsum[i] = 0.f;

    const int cbase = w * 2512;
    for (int tile = 0; tile < 157; tile++) {
        const int n = cbase + tile * 16 + n16;
        const ushort_t* bp = Wt + (size_t)n * 256 + q * 8;
        bf16x8 B[8];
#pragma unroll
        for (int kb = 0; kb < 8; kb++) B[kb] = *(const bf16x8*)(bp + kb * 32);
        const float obv = obp[n];
        f32x4 C[4];
#pragma unroll
        for (int mt = 0; mt < 4; mt++) {
            C[mt] = (f32x4){0.f, 0.f, 0.f, 0.f};
#pragma unroll
            for (int kb = 0; kb < 8; kb++)
                C[mt] = MFMA(A[mt][kb], B[kb], C[mt]);
        }
#pragma unroll
        for (int mt = 0; mt < 4; mt++)
#pragma unroll
            for (int r = 0; r < 4; r++) {
                const float sc = C[mt][r] + obv;
                if (n == yv[mt * 4 + r]) tgt64[mt * 16 + q * 4 + r] = sc;
                lsum[mt * 4 + r] += __expf(sc - 16.0f);
            }
    }
#pragma unroll
    for (int i = 0; i < 16; i++) {
        float v = lsum[i];
        v += __shfl_xor(v, 1, 16); v += __shfl_xor(v, 2, 16);
        v += __shfl_xor(v, 4, 16); v += __shfl_xor(v, 8, 16);
        lsum[i] = v;
    }
    if (n16 == 0)
#pragma unroll
        for (int i = 0; i < 16; i++)
            lsw[w][(i >> 2) * 16 + q * 4 + (i & 3)] = lsum[i];
    __syncthreads();

    if (tid < 64) {
        const float l = lsw[0][tid] + lsw[1][tid] + lsw[2][tid] + lsw[3][tid];
        const float lse = 16.0f + __logf(l);
        const int m = m0 + tid;
        const int tt = m >> 5, bb = m & 31;
        const int yvv = y[bb * SS + tt];
        float local = (yvv != 0) ? (lse - tgt64[tid]) / (32.0f * (float)lens[bb]) : 0.f;
        for (int off = 1; off < 64; off <<= 1) local += __shfl_xor(local, off, 64);
        if (tid == 0) atomicAdd(out, local);
    }
}

extern "C" void kernel_launch(void* const* d_in, const int* in_sizes, int n_in,
                              void* d_out, int out_size, void* d_ws, size_t ws_size,
                              hipStream_t stream)
{
    const int*   input_x = (const int*)  d_in[0];
    const int*   input_y = (const int*)  d_in[1];
    const int*   lens    = (const int*)  d_in[2];
    const float* emb_W   = (const float*)d_in[3];
    const float* k0      = (const float*)d_in[4];
    const float* b0      = (const float*)d_in[5];
    const float* k1      = (const float*)d_in[6];
    const float* b1      = (const float*)d_in[7];
    const float* out_W   = (const float*)d_in[8];
    const float* out_b   = (const float*)d_in[9];
    float* out = (float*)d_out;

    char* p = (char*)d_ws;
    ushort_t* Zsw  = (ushort_t*)p;  p += (size_t)SS * 512 * 64 * 2;   // 33.55 MB
    ushort_t* xzsw = (ushort_t*)p;  p += (size_t)SS * 512 * 64 * 2;   // 33.55 MB
    ushort_t* out1 = (ushort_t*)p;  p += (size_t)NROWS * 256 * 2;     // 8.39 MB
    ushort_t* h2bf = (ushort_t*)p;  p += (size_t)NROWS * 256 * 2;     // 8.39 MB
    ushort_t* W1h  = (ushort_t*)p;  p += (size_t)1024 * 256 * 2;
    ushort_t* W2h  = (ushort_t*)p;  p += (size_t)1024 * 256 * 2;
    ushort_t* W2x  = (ushort_t*)p;  p += (size_t)1024 * 256 * 2;
    ushort_t* Wt   = (ushort_t*)p;  p += (size_t)VPAD * 256 * 2;      // 5.14 MB
    float*    obp  = (float*)p;     p += (size_t)VPAD * 4;
    unsigned* c1   = (unsigned*)p;  p += 4;
    unsigned* xzf  = (unsigned*)p;  p += 128 * 4;

    hipMemsetAsync(d_out, 0, sizeof(float), stream);
    hipMemsetAsync(c1, 0, (1 + 128) * 4, stream);

    zgemm_sw<<<NROWS / 16, 256, 0, stream>>>(k0, b0, emb_W, input_x, Zsw);
    wtgen<<<dim3(16, 4), 256, 0, stream>>>(k0 + (size_t)EE * 1024, W1h);   // layer-1 h-part
    wtgen<<<dim3(16, 4), 256, 0, stream>>>(k1 + (size_t)HH * 1024, W2h);   // layer-2 h-part
    wtgen<<<dim3(16, 4), 256, 0, stream>>>(k1, W2x);                       // layer-2 x-part
    wtrans_kernel<<<dim3(VPAD / 64, 4), 256, 0, stream>>>(out_W, Wt);
    obset_kernel<<<(VPAD + 255) / 256, 256, 0, stream>>>(out_b, obp);
    pipe_kernel<<<130, 512, 0, stream>>>(W1h, W2h, W2x, b1, lens, Zsw,
                                         out1, xzsw, h2bf, c1, xzf);
    ce_kernel<<<NROWS / 64, 256, 0, stream>>>(h2bf, Wt, obp, input_y, lens, out);
}